// Round 9
// baseline (682.749 us; speedup 1.0000x reference)
//
#include <hip/hip_runtime.h>
#include <math.h>

// Problem constants
#define NA    50
#define NT    50
#define HIDK  128
#define NH    32
#define NC    16
#define NB    32
#define SAT   2500    // NA*NT
#define NS    2450    // (NA-1)*NT
#define NOUT  512     // NH*NC

// Bpart layout: [bh][which(2)][seg(51)][132]; AUXW floats of aux per bh
#define SEGW   132
#define WHICHW (51 * SEGW)     // 6732
#define BHW    (2 * WHICHW)    // 13464
#define AUXW   160

// ============ K0: PQ[j][k] = sum_c att[j][c] * W[(j%32)*16+c][k] ============
__global__ __launch_bounds__(256) void k0_pq(const float* __restrict__ W,
                                             const float* __restrict__ att_src,
                                             const float* __restrict__ att_dst,
                                             float* __restrict__ PQ) {
  int g = blockIdx.x * 256 + threadIdx.x;   // 8192 total
  int j = g >> 7, k = g & 127;
  int hh = j & 31;
  const float* att = (j < 32) ? att_src : att_dst;
  float acc = 0.f;
  #pragma unroll
  for (int c = 0; c < 16; ++c)
    acc = fmaf(att[hh * 16 + c], W[(size_t)(hh * 16 + c) * 128 + k], acc);
  PQ[g] = acc;
}

// ============ K1: u[b][h][s] = x_row . p_h ; d[b][h][t] = x_ego_row . q_h ============
__global__ __launch_bounds__(256) void k1_ud(
    const float* __restrict__ X,     // (80000,128)
    const float* __restrict__ PQ,    // (64,128)
    float* __restrict__ u,           // [b][h][2500]
    float* __restrict__ dv)          // [b][h][50]
{
  __shared__ float Ast[32][68];
  __shared__ float Bst[32][68];
  const int tid = threadIdx.x;
  const int m0 = blockIdx.x * 64;
  const int ty = tid >> 4, tx = tid & 15;
  float acc[4][4] = {};
  const int sr = tid >> 3, sc = tid & 7;

  for (int kc = 0; kc < 128; kc += 32) {
    #pragma unroll
    for (int L = 0; L < 2; ++L) {
      int row = sr + L * 32;
      float4 v = *(const float4*)&X[(size_t)(m0 + row) * 128 + kc + sc * 4];
      Ast[sc*4+0][row] = v.x; Ast[sc*4+1][row] = v.y;
      Ast[sc*4+2][row] = v.z; Ast[sc*4+3][row] = v.w;
      float4 w = *(const float4*)&PQ[(size_t)row * 128 + kc + sc * 4];
      Bst[sc*4+0][row] = w.x; Bst[sc*4+1][row] = w.y;
      Bst[sc*4+2][row] = w.z; Bst[sc*4+3][row] = w.w;
    }
    __syncthreads();
    #pragma unroll
    for (int k = 0; k < 32; ++k) {
      float4 a4 = *(const float4*)&Ast[k][ty * 4];
      float4 b4 = *(const float4*)&Bst[k][tx * 4];
      float a[4] = {a4.x, a4.y, a4.z, a4.w};
      float bb[4] = {b4.x, b4.y, b4.z, b4.w};
      #pragma unroll
      for (int i = 0; i < 4; ++i)
        #pragma unroll
        for (int j = 0; j < 4; ++j)
          acc[i][j] = fmaf(a[i], bb[j], acc[i][j]);
    }
    __syncthreads();
  }

  #pragma unroll
  for (int i = 0; i < 4; ++i) {
    int m = m0 + ty * 4 + i;
    int b = m / SAT, s = m - b * SAT;
    #pragma unroll
    for (int jj = 0; jj < 4; ++jj) {
      int col = tx * 4 + jj;
      if (col < 32)
        u[(size_t)(b * 32 + col) * SAT + s] = acc[i][jj];
      else if (s < NT)
        dv[(size_t)(b * 32 + col - 32) * NT + s] = acc[i][jj];
    }
  }
}

// ============ K2a: sort + bucket partial sums -> global (no Bb/W in LDS) ============
// R8 lesson: 78.8KB LDS capped us at 16 waves/CU and the compiler wouldn't fund
// a register pipeline. Here LDS ~36KB -> 4 blocks/CU x 8 waves = 32 waves/CU
// (hardware cap); bucket sums flush straight to global (exclusive, coalesced,
// no atomics); scans/projection/output deferred to k2b.
#define LOADG(B_, g_) do {                                                  \
    _Pragma("unroll")                                                       \
    for (int j = 0; j < 4; ++j) {                                           \
      int idx_ = base + 2 * ((g_) * 4 + j);                                 \
      e##B_[j] = sE[idx_]; s##B_[j] = sIdx[idx_];                           \
    }                                                                       \
    _Pragma("unroll")                                                       \
    for (int j = 0; j < 4; ++j)                                             \
      x##B_[j] = *(const float4*)(xb + (size_t)s##B_[j] * HIDK);            \
  } while (0)

#define COMPG(B_) do {                                                      \
    _Pragma("unroll")                                                       \
    for (int j = 0; j < 4; ++j) {                                           \
      float2 ee = e##B_[j]; float4 xx = x##B_[j];                           \
      a1[0]=fmaf(ee.x,xx.x,a1[0]); a1[1]=fmaf(ee.x,xx.y,a1[1]);             \
      a1[2]=fmaf(ee.x,xx.z,a1[2]); a1[3]=fmaf(ee.x,xx.w,a1[3]);             \
      a2[0]=fmaf(ee.y,xx.x,a2[0]); a2[1]=fmaf(ee.y,xx.y,a2[1]);             \
      a2[2]=fmaf(ee.y,xx.z,a2[2]); a2[3]=fmaf(ee.y,xx.w,a2[3]);             \
      z1 += ee.x; z2 += ee.y;                                               \
    }                                                                       \
  } while (0)

__global__ __launch_bounds__(512, 8) void k2a_gather(
    const float* __restrict__ X,     // (32,2500,128)
    const float* __restrict__ u,     // [b][h][2500]
    const float* __restrict__ dv,    // [b][h][50]
    float* __restrict__ Bpart,       // [bh][2][51][132]
    float* __restrict__ aux)         // [bh][160]: F1[50] F2[50] rank[50]
{
  const int id = blockIdx.x;
  const int b  = (id & 7) + 8 * (id >> 8);   // XCD-locality for X slices
  const int h  = (id >> 3) & 31;
  const int tid = threadIdx.x;
  const int bh = b * 32 + h;

  __shared__ float2 sE[NS];          // sorted (e1,e2)   19.6 KB
  __shared__ float  sU[NS];          // raw u             9.8 KB
  __shared__ unsigned short sIdx[NS];// sorted sat-index  4.9 KB
  __shared__ float sTheta[50], sD[50];
  __shared__ int   sRank[50];
  __shared__ int   offs[52];
  __shared__ int   offCur[51];
  __shared__ float red[8];
  __shared__ float sMaxU;

  const float* uP = u + (size_t)bh * SAT + NT;   // skip ego rows
  for (int i = tid; i < NS; i += 512) sU[i] = uP[i];
  if (tid < 50) sD[tid] = dv[(size_t)bh * NT + tid];
  if (tid < 51) offCur[tid] = 0;
  __syncthreads();

  // ---- maxU ----
  float mx = -1e30f;
  for (int i = tid; i < NS; i += 512) mx = fmaxf(mx, sU[i]);
  #pragma unroll
  for (int o = 32; o; o >>= 1) mx = fmaxf(mx, __shfl_xor(mx, o));
  if ((tid & 63) == 0) red[tid >> 6] = mx;
  __syncthreads();
  if (tid == 0) {
    float m2 = red[0];
    #pragma unroll
    for (int k = 1; k < 8; ++k) m2 = fmaxf(m2, red[k]);
    sMaxU = m2;
  }
  __syncthreads();
  const float maxU = sMaxU;

  // ---- theta rank-sort + per-query factors -> aux ----
  if (tid < 50) {
    float th = -sD[tid];
    int r = 0;
    for (int t2 = 0; t2 < 50; ++t2) {
      float th2 = -sD[t2];
      r += (th2 < th) || (th2 == th && t2 < tid);
    }
    sRank[tid] = r;
    sTheta[r] = th;
    float x = maxU + sD[tid];
    float L = (x >= 0.f) ? x : 0.2f * x;
    float* ax = aux + (size_t)bh * AUXW;
    ax[tid]       = __expf(x - L);         // F1
    ax[50 + tid]  = __expf(0.2f * x - L);  // F2
    ax[100 + tid] = (float)r;              // rank
  }
  __syncthreads();

  // ---- histogram ----
  for (int i = tid; i < NS; i += 512) {
    float uu = sU[i];
    int lo = 0, hi = 50;
    while (lo < hi) { int mid = (lo + hi) >> 1; if (sTheta[mid] <= uu) lo = mid + 1; else hi = mid; }
    atomicAdd(&offCur[lo], 1);
  }
  __syncthreads();
  if (tid == 0) {
    int run = 0;
    for (int k = 0; k < 51; ++k) { int c = offCur[k]; offs[k] = run; run += c; }
    offs[51] = run;  // 2450
  }
  __syncthreads();
  if (tid < 51) offCur[tid] = offs[tid];
  __syncthreads();

  // ---- scatter: sorted (e1,e2,satIdx) (re-search: cheaper than 4.9KB beta) ----
  for (int i = tid; i < NS; i += 512) {
    float uu = sU[i];
    int lo = 0, hi = 50;
    while (lo < hi) { int mid = (lo + hi) >> 1; if (sTheta[mid] <= uu) lo = mid + 1; else hi = mid; }
    int pos = atomicAdd(&offCur[lo], 1);
    sE[pos] = make_float2(__expf(uu - maxU), __expf(0.2f * (uu - maxU)));
    sIdx[pos] = (unsigned short)(i + NT);
  }
  __syncthreads();

  // ---- F: wave-owned segments, pipelined gather, flush to GLOBAL ----
  {
    const int wave = tid >> 6;        // 0..7
    const int lane = tid & 63;
    const int slot = lane >> 5;       // which source of the pair
    const int cq   = lane & 31;       // channel quad cq*4..+3
    const float* xb = X + (size_t)b * SAT * HIDK + cq * 4;
    float* bp = Bpart + (size_t)bh * BHW;

    for (int seg = wave; seg < 51; seg += 8) {
      const int i0 = offs[seg], i1 = offs[seg + 1];
      const int base = i0 + slot;
      int np = i1 - base;
      np = (np > 0) ? ((np + 1) >> 1) : 0;
      const int G = np >> 2;

      float a1[4] = {0.f, 0.f, 0.f, 0.f};
      float a2[4] = {0.f, 0.f, 0.f, 0.f};
      float z1 = 0.f, z2 = 0.f;

      float2 eA[4], eB[4]; int sA[4], sB[4]; float4 xA[4], xB[4];
      int g = 0;
      if (G) LOADG(A, 0);
      while (g + 2 <= G) {
        LOADG(B, g + 1);
        COMPG(A);
        if (g + 2 < G) LOADG(A, g + 2);
        COMPG(B);
        g += 2;
      }
      if (g < G) COMPG(A);
      for (int k = G * 4; k < np; ++k) {
        int idx = base + 2 * k;
        float2 ee = sE[idx];
        int ss = sIdx[idx];
        float4 xx = *(const float4*)(xb + (size_t)ss * HIDK);
        a1[0]=fmaf(ee.x,xx.x,a1[0]); a1[1]=fmaf(ee.x,xx.y,a1[1]);
        a1[2]=fmaf(ee.x,xx.z,a1[2]); a1[3]=fmaf(ee.x,xx.w,a1[3]);
        a2[0]=fmaf(ee.y,xx.x,a2[0]); a2[1]=fmaf(ee.y,xx.y,a2[1]);
        a2[2]=fmaf(ee.y,xx.z,a2[2]); a2[3]=fmaf(ee.y,xx.w,a2[3]);
        z1 += ee.x; z2 += ee.y;
      }

      #pragma unroll
      for (int j = 0; j < 4; ++j) {
        a1[j] += __shfl_xor(a1[j], 32);
        a2[j] += __shfl_xor(a2[j], 32);
      }
      z1 += __shfl_xor(z1, 32);
      z2 += __shfl_xor(z2, 32);
      if (slot == 0) {
        float4 st1 = {a1[0], a1[1], a1[2], a1[3]};
        float4 st2 = {a2[0], a2[1], a2[2], a2[3]};
        *(float4*)&bp[seg * SEGW + cq * 4] = st1;
        *(float4*)&bp[WHICHW + seg * SEGW + cq * 4] = st2;
        if (cq == 0) {
          bp[seg * SEGW + 128] = z1;
          bp[WHICHW + seg * SEGW + 128] = z2;
        }
      }
    }
  }
}

// ============ K2b: scans + projection + ego write + bias fill ============
__global__ __launch_bounds__(256) void k2b_out(
    const float* __restrict__ Bpart, const float* __restrict__ aux,
    const float* __restrict__ W, const float* __restrict__ bias,
    float* __restrict__ out)
{
  const int h = blockIdx.x & 31;
  const int b = blockIdx.x >> 5;
  const int bh = b * 32 + h;
  const int tid = threadIdx.x;

  __shared__ float Bb[2][51][SEGW];   // 53.9 KB
  __shared__ float WshT[128][16];     //  8.0 KB
  __shared__ float sF1[50], sF2[50];
  __shared__ int   sRank[50];
  __shared__ float sBias[512];

  // stage partials, aux, W_h^T, bias
  {
    const float4* src = (const float4*)(Bpart + (size_t)bh * BHW);
    float4* dst = (float4*)&Bb[0][0][0];
    for (int i = tid; i < BHW / 4; i += 256) dst[i] = src[i];
  }
  if (tid < 50) {
    const float* ax = aux + (size_t)bh * AUXW;
    sF1[tid] = ax[tid];
    sF2[tid] = ax[50 + tid];
    sRank[tid] = (int)ax[100 + tid];
  }
  {
    const float* Wh = W + (size_t)h * 16 * 128;
    for (int v = tid; v < 2048; v += 256) {
      int k = v >> 4, cout = v & 15;
      WshT[k][cout] = Wh[(size_t)cout * 128 + k];
    }
    for (int i = tid; i < 512; i += 256) sBias[i] = bias[i];
  }
  __syncthreads();

  // scans: which=0 -> exclusive suffix, which=1 -> inclusive prefix (129 ch)
  for (int task = tid; task < 258; task += 256) {
    int which = task >= 129;
    int c = task - which * 129;
    if (which == 0) {
      float run = 0.f;
      for (int k = 50; k >= 0; --k) { float tmp = Bb[0][k][c]; Bb[0][k][c] = run; run += tmp; }
    } else {
      float run = 0.f;
      for (int k = 0; k <= 50; ++k) { run += Bb[1][k][c]; Bb[1][k][c] = run; }
    }
  }

  // bias fill of this block's share of non-ego rows (independent of scans)
  {
    const int r0 = (NS * h) >> 5;
    const int r1 = (NS * (h + 1)) >> 5;
    const int n = (r1 - r0) * 128;
    float4* outp = (float4*)out;
    const float4* bv = (const float4*)sBias;
    for (int j = tid; j < n; j += 256) {
      int row = r0 + (j >> 7), c4 = j & 127;
      outp[((size_t)b * SAT + NT + row) * 128 + c4] = bv[c4];
    }
  }
  __syncthreads();

  // projection epilogue: 800 tasks grid-stride (R3 lesson)
  for (int task = tid; task < NT * NC; task += 256) {
    int t = task >> 4, cout = task & 15;
    int r = sRank[t];
    float F1 = sF1[t], F2 = sF2[t];
    float z = F1 * Bb[0][r][128] + F2 * Bb[1][r][128];
    const float* b1r = &Bb[0][r][0];
    const float* b2r = &Bb[1][r][0];
    float n1 = 0.f, n2 = 0.f;
    #pragma unroll 4
    for (int c = 0; c < 128; ++c) {
      float w = WshT[c][cout];
      n1 = fmaf(b1r[c], w, n1);
      n2 = fmaf(b2r[c], w, n2);
    }
    out[((size_t)b * SAT + t) * NOUT + h * 16 + cout] =
        (F1 * n1 + F2 * n2) / z + sBias[h * 16 + cout];
  }
}

extern "C" void kernel_launch(void* const* d_in, const int* in_sizes, int n_in,
                              void* d_out, int out_size, void* d_ws, size_t ws_size,
                              hipStream_t stream) {
  const float* X       = (const float*)d_in[0];  // h (32,50,50,128)
  const float* Wm      = (const float*)d_in[1];  // W (512,128)
  const float* att_src = (const float*)d_in[2];  // (32,16)
  const float* att_dst = (const float*)d_in[3];  // (32,16)
  const float* bias    = (const float*)d_in[4];  // (512,)
  float* out = (float*)d_out;

  // workspace: PQ 8192 | u 2.56M | dv 51.2K | aux 163.8K | Bpart 13.79M floats (~66.3 MB)
  float* PQ   = (float*)d_ws;
  float* u    = PQ + 64 * 128;
  float* dv   = u + (size_t)NB * NH * SAT;
  float* aux  = dv + (size_t)NB * NH * NT;
  float* Bpart = aux + (size_t)NB * NH * AUXW;

  hipLaunchKernelGGL(k0_pq, dim3(32), dim3(256), 0, stream, Wm, att_src, att_dst, PQ);
  hipLaunchKernelGGL(k1_ud, dim3(1250), dim3(256), 0, stream, X, PQ, u, dv);
  hipLaunchKernelGGL(k2a_gather, dim3(1024), dim3(512), 0, stream, X, u, dv, Bpart, aux);
  hipLaunchKernelGGL(k2b_out, dim3(1024), dim3(256), 0, stream, Bpart, aux, Wm, bias, out);
}

// Round 10
// 338.730 us; speedup vs baseline: 2.0156x; 2.0156x over previous
//
#include <hip/hip_runtime.h>
#include <math.h>

// Problem constants
#define NA    50
#define NT    50
#define HIDK  128
#define NH    32
#define NC    16
#define NB    32
#define SAT   2500    // NA*NT
#define NS    2450    // (NA-1)*NT
#define NOUT  512     // NH*NC

// Bpart layout: [bh][which(2)][seg(51)][132]; AUXW floats of aux per bh
#define SEGW   132
#define WHICHW (51 * SEGW)     // 6732
#define BHW    (2 * WHICHW)    // 13464
#define AUXW   160

// ============ K0: PQ[j][k] = sum_c att[j][c] * W[(j%32)*16+c][k] ============
__global__ __launch_bounds__(256) void k0_pq(const float* __restrict__ W,
                                             const float* __restrict__ att_src,
                                             const float* __restrict__ att_dst,
                                             float* __restrict__ PQ) {
  int g = blockIdx.x * 256 + threadIdx.x;   // 8192 total
  int j = g >> 7, k = g & 127;
  int hh = j & 31;
  const float* att = (j < 32) ? att_src : att_dst;
  float acc = 0.f;
  #pragma unroll
  for (int c = 0; c < 16; ++c)
    acc = fmaf(att[hh * 16 + c], W[(size_t)(hh * 16 + c) * 128 + k], acc);
  PQ[g] = acc;
}

// ============ K1: u[b][h][s] = x_row . p_h ; d[b][h][t] = x_ego_row . q_h ============
__global__ __launch_bounds__(256) void k1_ud(
    const float* __restrict__ X,     // (80000,128)
    const float* __restrict__ PQ,    // (64,128)
    float* __restrict__ u,           // [b][h][2500]
    float* __restrict__ dv)          // [b][h][50]
{
  __shared__ float Ast[32][68];
  __shared__ float Bst[32][68];
  const int tid = threadIdx.x;
  const int m0 = blockIdx.x * 64;
  const int ty = tid >> 4, tx = tid & 15;
  float acc[4][4] = {};
  const int sr = tid >> 3, sc = tid & 7;

  for (int kc = 0; kc < 128; kc += 32) {
    #pragma unroll
    for (int L = 0; L < 2; ++L) {
      int row = sr + L * 32;
      float4 v = *(const float4*)&X[(size_t)(m0 + row) * 128 + kc + sc * 4];
      Ast[sc*4+0][row] = v.x; Ast[sc*4+1][row] = v.y;
      Ast[sc*4+2][row] = v.z; Ast[sc*4+3][row] = v.w;
      float4 w = *(const float4*)&PQ[(size_t)row * 128 + kc + sc * 4];
      Bst[sc*4+0][row] = w.x; Bst[sc*4+1][row] = w.y;
      Bst[sc*4+2][row] = w.z; Bst[sc*4+3][row] = w.w;
    }
    __syncthreads();
    #pragma unroll
    for (int k = 0; k < 32; ++k) {
      float4 a4 = *(const float4*)&Ast[k][ty * 4];
      float4 b4 = *(const float4*)&Bst[k][tx * 4];
      float a[4] = {a4.x, a4.y, a4.z, a4.w};
      float bb[4] = {b4.x, b4.y, b4.z, b4.w};
      #pragma unroll
      for (int i = 0; i < 4; ++i)
        #pragma unroll
        for (int j = 0; j < 4; ++j)
          acc[i][j] = fmaf(a[i], bb[j], acc[i][j]);
    }
    __syncthreads();
  }

  #pragma unroll
  for (int i = 0; i < 4; ++i) {
    int m = m0 + ty * 4 + i;
    int b = m / SAT, s = m - b * SAT;
    #pragma unroll
    for (int jj = 0; jj < 4; ++jj) {
      int col = tx * 4 + jj;
      if (col < 32)
        u[(size_t)(b * 32 + col) * SAT + s] = acc[i][jj];
      else if (s < NT)
        dv[(size_t)(b * 32 + col - 32) * NT + s] = acc[i][jj];
    }
  }
}

// ============ K2a: sort + bucket partial sums -> global ============
// R9 lesson: (512,8) + register pipeline = 32 VGPRs + 2GB scratch spill.
// This loop lives at ~52 VGPR (R7) — keep the SIMPLE x4 unroll, fit the
// 64-VGPR budget, and take 4 blocks/CU x 8 waves = 32 waves/CU for latency
// hiding via TLP instead of registers.
__global__ __launch_bounds__(512, 8) void k2a_gather(
    const float* __restrict__ X,     // (32,2500,128)
    const float* __restrict__ u,     // [b][h][2500]
    const float* __restrict__ dv,    // [b][h][50]
    float* __restrict__ Bpart,       // [bh][2][51][132]
    float* __restrict__ aux)         // [bh][160]: F1[50] F2[50] rank[50]
{
  const int id = blockIdx.x;
  const int b  = (id & 7) + 8 * (id >> 8);   // XCD gets 4 b-slices (5MB) -> L2/L3
  const int h  = (id >> 3) & 31;
  const int tid = threadIdx.x;
  const int bh = b * 32 + h;

  __shared__ float2 sE[NS];          // sorted (e1,e2)   19.6 KB
  __shared__ float  sU[NS];          // raw u             9.8 KB
  __shared__ unsigned short sIdx[NS];// sorted sat-index  4.9 KB
  __shared__ float sTheta[50], sD[50];
  __shared__ int   offs[52];
  __shared__ int   offCur[51];
  __shared__ float red[8];
  __shared__ float sMaxU;

  const float* uP = u + (size_t)bh * SAT + NT;   // skip ego rows
  for (int i = tid; i < NS; i += 512) sU[i] = uP[i];
  if (tid < 50) sD[tid] = dv[(size_t)bh * NT + tid];
  if (tid < 51) offCur[tid] = 0;
  __syncthreads();

  // ---- maxU ----
  float mx = -1e30f;
  for (int i = tid; i < NS; i += 512) mx = fmaxf(mx, sU[i]);
  #pragma unroll
  for (int o = 32; o; o >>= 1) mx = fmaxf(mx, __shfl_xor(mx, o));
  if ((tid & 63) == 0) red[tid >> 6] = mx;
  __syncthreads();
  if (tid == 0) {
    float m2 = red[0];
    #pragma unroll
    for (int k = 1; k < 8; ++k) m2 = fmaxf(m2, red[k]);
    sMaxU = m2;
  }
  __syncthreads();
  const float maxU = sMaxU;

  // ---- theta rank-sort + per-query factors -> aux ----
  if (tid < 50) {
    float th = -sD[tid];
    int r = 0;
    for (int t2 = 0; t2 < 50; ++t2) {
      float th2 = -sD[t2];
      r += (th2 < th) || (th2 == th && t2 < tid);
    }
    sTheta[r] = th;
    float x = maxU + sD[tid];
    float L = (x >= 0.f) ? x : 0.2f * x;
    float* ax = aux + (size_t)bh * AUXW;
    ax[tid]       = __expf(x - L);         // F1
    ax[50 + tid]  = __expf(0.2f * x - L);  // F2
    ax[100 + tid] = (float)r;              // rank
  }
  __syncthreads();

  // ---- histogram ----
  for (int i = tid; i < NS; i += 512) {
    float uu = sU[i];
    int lo = 0, hi = 50;
    while (lo < hi) { int mid = (lo + hi) >> 1; if (sTheta[mid] <= uu) lo = mid + 1; else hi = mid; }
    atomicAdd(&offCur[lo], 1);
  }
  __syncthreads();
  if (tid == 0) {
    int run = 0;
    for (int k = 0; k < 51; ++k) { int c = offCur[k]; offs[k] = run; run += c; }
    offs[51] = run;  // 2450
  }
  __syncthreads();
  if (tid < 51) offCur[tid] = offs[tid];
  __syncthreads();

  // ---- scatter: sorted (e1,e2,satIdx) ----
  for (int i = tid; i < NS; i += 512) {
    float uu = sU[i];
    int lo = 0, hi = 50;
    while (lo < hi) { int mid = (lo + hi) >> 1; if (sTheta[mid] <= uu) lo = mid + 1; else hi = mid; }
    int pos = atomicAdd(&offCur[lo], 1);
    sE[pos] = make_float2(__expf(uu - maxU), __expf(0.2f * (uu - maxU)));
    sIdx[pos] = (unsigned short)(i + NT);
  }
  __syncthreads();

  // ---- F: wave-owned segments, simple x4 unroll (52 VGPR), flush to GLOBAL ----
  {
    const int wave = tid >> 6;        // 0..7
    const int lane = tid & 63;
    const int slot = lane >> 5;       // which source of the pair
    const int cq   = lane & 31;       // channel quad cq*4..+3
    const float* xb = X + (size_t)b * SAT * HIDK + cq * 4;
    float* bp = Bpart + (size_t)bh * BHW;

    for (int seg = wave; seg < 51; seg += 8) {
      const int i0 = offs[seg], i1 = offs[seg + 1];
      float a1[4] = {0.f, 0.f, 0.f, 0.f};
      float a2[4] = {0.f, 0.f, 0.f, 0.f};
      float z1 = 0.f, z2 = 0.f;
      int i = i0 + slot;
      for (; i + 6 < i1; i += 8) {
        float2 e0 = sE[i];     float2 e1 = sE[i + 2];
        float2 e2 = sE[i + 4]; float2 e3 = sE[i + 6];
        int s0 = sIdx[i];     int s1 = sIdx[i + 2];
        int s2 = sIdx[i + 4]; int s3 = sIdx[i + 6];
        float4 x0 = *(const float4*)(xb + (size_t)s0 * HIDK);
        float4 x1 = *(const float4*)(xb + (size_t)s1 * HIDK);
        float4 x2 = *(const float4*)(xb + (size_t)s2 * HIDK);
        float4 x3 = *(const float4*)(xb + (size_t)s3 * HIDK);
        a1[0] = fmaf(e0.x, x0.x, a1[0]); a1[1] = fmaf(e0.x, x0.y, a1[1]);
        a1[2] = fmaf(e0.x, x0.z, a1[2]); a1[3] = fmaf(e0.x, x0.w, a1[3]);
        a2[0] = fmaf(e0.y, x0.x, a2[0]); a2[1] = fmaf(e0.y, x0.y, a2[1]);
        a2[2] = fmaf(e0.y, x0.z, a2[2]); a2[3] = fmaf(e0.y, x0.w, a2[3]);
        z1 += e0.x; z2 += e0.y;
        a1[0] = fmaf(e1.x, x1.x, a1[0]); a1[1] = fmaf(e1.x, x1.y, a1[1]);
        a1[2] = fmaf(e1.x, x1.z, a1[2]); a1[3] = fmaf(e1.x, x1.w, a1[3]);
        a2[0] = fmaf(e1.y, x1.x, a2[0]); a2[1] = fmaf(e1.y, x1.y, a2[1]);
        a2[2] = fmaf(e1.y, x1.z, a2[2]); a2[3] = fmaf(e1.y, x1.w, a2[3]);
        z1 += e1.x; z2 += e1.y;
        a1[0] = fmaf(e2.x, x2.x, a1[0]); a1[1] = fmaf(e2.x, x2.y, a1[1]);
        a1[2] = fmaf(e2.x, x2.z, a1[2]); a1[3] = fmaf(e2.x, x2.w, a1[3]);
        a2[0] = fmaf(e2.y, x2.x, a2[0]); a2[1] = fmaf(e2.y, x2.y, a2[1]);
        a2[2] = fmaf(e2.y, x2.z, a2[2]); a2[3] = fmaf(e2.y, x2.w, a2[3]);
        z1 += e2.x; z2 += e2.y;
        a1[0] = fmaf(e3.x, x3.x, a1[0]); a1[1] = fmaf(e3.x, x3.y, a1[1]);
        a1[2] = fmaf(e3.x, x3.z, a1[2]); a1[3] = fmaf(e3.x, x3.w, a1[3]);
        a2[0] = fmaf(e3.y, x3.x, a2[0]); a2[1] = fmaf(e3.y, x3.y, a2[1]);
        a2[2] = fmaf(e3.y, x3.z, a2[2]); a2[3] = fmaf(e3.y, x3.w, a2[3]);
        z1 += e3.x; z2 += e3.y;
      }
      for (; i < i1; i += 2) {
        float2 e = sE[i];
        int s = sIdx[i];
        float4 xv = *(const float4*)(xb + (size_t)s * HIDK);
        a1[0] = fmaf(e.x, xv.x, a1[0]); a1[1] = fmaf(e.x, xv.y, a1[1]);
        a1[2] = fmaf(e.x, xv.z, a1[2]); a1[3] = fmaf(e.x, xv.w, a1[3]);
        a2[0] = fmaf(e.y, xv.x, a2[0]); a2[1] = fmaf(e.y, xv.y, a2[1]);
        a2[2] = fmaf(e.y, xv.z, a2[2]); a2[3] = fmaf(e.y, xv.w, a2[3]);
        z1 += e.x; z2 += e.y;
      }
      // combine slots; exclusive coalesced flush (no atomics)
      #pragma unroll
      for (int j = 0; j < 4; ++j) {
        a1[j] += __shfl_xor(a1[j], 32);
        a2[j] += __shfl_xor(a2[j], 32);
      }
      z1 += __shfl_xor(z1, 32);
      z2 += __shfl_xor(z2, 32);
      if (slot == 0) {
        float4 st1 = {a1[0], a1[1], a1[2], a1[3]};
        float4 st2 = {a2[0], a2[1], a2[2], a2[3]};
        *(float4*)&bp[seg * SEGW + cq * 4] = st1;
        *(float4*)&bp[WHICHW + seg * SEGW + cq * 4] = st2;
        if (cq == 0) {
          bp[seg * SEGW + 128] = z1;
          bp[WHICHW + seg * SEGW + 128] = z2;
        }
      }
    }
  }
}

// ============ K2b: scans + projection + ego write + bias fill ============
__global__ __launch_bounds__(256) void k2b_out(
    const float* __restrict__ Bpart, const float* __restrict__ aux,
    const float* __restrict__ W, const float* __restrict__ bias,
    float* __restrict__ out)
{
  const int h = blockIdx.x & 31;
  const int b = blockIdx.x >> 5;
  const int bh = b * 32 + h;
  const int tid = threadIdx.x;

  __shared__ float Bb[2][51][SEGW];   // 53.9 KB
  __shared__ float WshT[128][16];     //  8.0 KB
  __shared__ float sF1[50], sF2[50];
  __shared__ int   sRank[50];
  __shared__ float sBias[512];

  // stage partials, aux, W_h^T, bias
  {
    const float4* src = (const float4*)(Bpart + (size_t)bh * BHW);
    float4* dst = (float4*)&Bb[0][0][0];
    for (int i = tid; i < BHW / 4; i += 256) dst[i] = src[i];
  }
  if (tid < 50) {
    const float* ax = aux + (size_t)bh * AUXW;
    sF1[tid] = ax[tid];
    sF2[tid] = ax[50 + tid];
    sRank[tid] = (int)ax[100 + tid];
  }
  {
    const float* Wh = W + (size_t)h * 16 * 128;
    for (int v = tid; v < 2048; v += 256) {
      int k = v >> 4, cout = v & 15;
      WshT[k][cout] = Wh[(size_t)cout * 128 + k];
    }
    for (int i = tid; i < 512; i += 256) sBias[i] = bias[i];
  }
  __syncthreads();

  // scans: which=0 -> exclusive suffix, which=1 -> inclusive prefix (129 ch)
  for (int task = tid; task < 258; task += 256) {
    int which = task >= 129;
    int c = task - which * 129;
    if (which == 0) {
      float run = 0.f;
      for (int k = 50; k >= 0; --k) { float tmp = Bb[0][k][c]; Bb[0][k][c] = run; run += tmp; }
    } else {
      float run = 0.f;
      for (int k = 0; k <= 50; ++k) { run += Bb[1][k][c]; Bb[1][k][c] = run; }
    }
  }

  // bias fill of this block's share of non-ego rows (independent of scans)
  {
    const int r0 = (NS * h) >> 5;
    const int r1 = (NS * (h + 1)) >> 5;
    const int n = (r1 - r0) * 128;
    float4* outp = (float4*)out;
    const float4* bv = (const float4*)sBias;
    for (int j = tid; j < n; j += 256) {
      int row = r0 + (j >> 7), c4 = j & 127;
      outp[((size_t)b * SAT + NT + row) * 128 + c4] = bv[c4];
    }
  }
  __syncthreads();

  // projection epilogue: 800 tasks grid-stride (R3 lesson)
  for (int task = tid; task < NT * NC; task += 256) {
    int t = task >> 4, cout = task & 15;
    int r = sRank[t];
    float F1 = sF1[t], F2 = sF2[t];
    float z = F1 * Bb[0][r][128] + F2 * Bb[1][r][128];
    const float* b1r = &Bb[0][r][0];
    const float* b2r = &Bb[1][r][0];
    float n1 = 0.f, n2 = 0.f;
    #pragma unroll 4
    for (int c = 0; c < 128; ++c) {
      float w = WshT[c][cout];
      n1 = fmaf(b1r[c], w, n1);
      n2 = fmaf(b2r[c], w, n2);
    }
    out[((size_t)b * SAT + t) * NOUT + h * 16 + cout] =
        (F1 * n1 + F2 * n2) / z + sBias[h * 16 + cout];
  }
}

extern "C" void kernel_launch(void* const* d_in, const int* in_sizes, int n_in,
                              void* d_out, int out_size, void* d_ws, size_t ws_size,
                              hipStream_t stream) {
  const float* X       = (const float*)d_in[0];  // h (32,50,50,128)
  const float* Wm      = (const float*)d_in[1];  // W (512,128)
  const float* att_src = (const float*)d_in[2];  // (32,16)
  const float* att_dst = (const float*)d_in[3];  // (32,16)
  const float* bias    = (const float*)d_in[4];  // (512,)
  float* out = (float*)d_out;

  // workspace: PQ 8192 | u 2.56M | dv 51.2K | aux 163.8K | Bpart 13.79M floats (~66.3 MB)
  float* PQ   = (float*)d_ws;
  float* u    = PQ + 64 * 128;
  float* dv   = u + (size_t)NB * NH * SAT;
  float* aux  = dv + (size_t)NB * NH * NT;
  float* Bpart = aux + (size_t)NB * NH * AUXW;

  hipLaunchKernelGGL(k0_pq, dim3(32), dim3(256), 0, stream, Wm, att_src, att_dst, PQ);
  hipLaunchKernelGGL(k1_ud, dim3(1250), dim3(256), 0, stream, X, PQ, u, dv);
  hipLaunchKernelGGL(k2a_gather, dim3(1024), dim3(512), 0, stream, X, u, dv, Bpart, aux);
  hipLaunchKernelGGL(k2b_out, dim3(1024), dim3(256), 0, stream, Bpart, aux, Wm, bias, out);
}

// Round 11
// 327.950 us; speedup vs baseline: 2.0819x; 1.0329x over previous
//
#include <hip/hip_runtime.h>
#include <math.h>

// Problem constants
#define NA    50
#define NT    50
#define HIDK  128
#define NH    32
#define NC    16
#define NB    32
#define SAT   2500    // NA*NT
#define NS    2450    // (NA-1)*NT
#define NOUT  512     // NH*NC

// Bpart layout: [bh][which(2)][seg(51)][132]; AUXW floats of aux per bh
#define SEGW   132
#define WHICHW (51 * SEGW)     // 6732
#define BHW    (2 * WHICHW)    // 13464
#define AUXW   160

// ============ K0: PQ[j][k] = sum_c att[j][c] * W[(j%32)*16+c][k] ============
__global__ __launch_bounds__(256) void k0_pq(const float* __restrict__ W,
                                             const float* __restrict__ att_src,
                                             const float* __restrict__ att_dst,
                                             float* __restrict__ PQ) {
  int g = blockIdx.x * 256 + threadIdx.x;   // 8192 total
  int j = g >> 7, k = g & 127;
  int hh = j & 31;
  const float* att = (j < 32) ? att_src : att_dst;
  float acc = 0.f;
  #pragma unroll
  for (int c = 0; c < 16; ++c)
    acc = fmaf(att[hh * 16 + c], W[(size_t)(hh * 16 + c) * 128 + k], acc);
  PQ[g] = acc;
}

// ============ K1: u[b][h][s] = x_row . p_h ; d[b][h][t] = x_ego_row . q_h ============
__global__ __launch_bounds__(256) void k1_ud(
    const float* __restrict__ X,     // (80000,128)
    const float* __restrict__ PQ,    // (64,128)
    float* __restrict__ u,           // [b][h][2500]
    float* __restrict__ dv)          // [b][h][50]
{
  __shared__ float Ast[32][68];
  __shared__ float Bst[32][68];
  const int tid = threadIdx.x;
  const int m0 = blockIdx.x * 64;
  const int ty = tid >> 4, tx = tid & 15;
  float acc[4][4] = {};
  const int sr = tid >> 3, sc = tid & 7;

  for (int kc = 0; kc < 128; kc += 32) {
    #pragma unroll
    for (int L = 0; L < 2; ++L) {
      int row = sr + L * 32;
      float4 v = *(const float4*)&X[(size_t)(m0 + row) * 128 + kc + sc * 4];
      Ast[sc*4+0][row] = v.x; Ast[sc*4+1][row] = v.y;
      Ast[sc*4+2][row] = v.z; Ast[sc*4+3][row] = v.w;
      float4 w = *(const float4*)&PQ[(size_t)row * 128 + kc + sc * 4];
      Bst[sc*4+0][row] = w.x; Bst[sc*4+1][row] = w.y;
      Bst[sc*4+2][row] = w.z; Bst[sc*4+3][row] = w.w;
    }
    __syncthreads();
    #pragma unroll
    for (int k = 0; k < 32; ++k) {
      float4 a4 = *(const float4*)&Ast[k][ty * 4];
      float4 b4 = *(const float4*)&Bst[k][tx * 4];
      float a[4] = {a4.x, a4.y, a4.z, a4.w};
      float bb[4] = {b4.x, b4.y, b4.z, b4.w};
      #pragma unroll
      for (int i = 0; i < 4; ++i)
        #pragma unroll
        for (int j = 0; j < 4; ++j)
          acc[i][j] = fmaf(a[i], bb[j], acc[i][j]);
    }
    __syncthreads();
  }

  #pragma unroll
  for (int i = 0; i < 4; ++i) {
    int m = m0 + ty * 4 + i;
    int b = m / SAT, s = m - b * SAT;
    #pragma unroll
    for (int jj = 0; jj < 4; ++jj) {
      int col = tx * 4 + jj;
      if (col < 32)
        u[(size_t)(b * 32 + col) * SAT + s] = acc[i][jj];
      else if (s < NT)
        dv[(size_t)(b * 32 + col - 32) * NT + s] = acc[i][jj];
    }
  }
}

// ============ K2a: sort + bucket partial sums -> global ============
// R9/R10 lesson: __launch_bounds__(512,8) made the allocator pick 32 VGPR and
// SPILL the x4-unrolled loop (WRITE_SIZE 1.2GB, VALUBusy 8%). Unbounded, this
// loop compiles to ~52 VGPR (R7) which already fits 8 waves/EU. LDS trimmed
// to ~26KB (u re-read from L2 instead of staged) -> 4 blocks/CU.
__global__ __launch_bounds__(512) void k2a_gather(
    const float* __restrict__ X,     // (32,2500,128)
    const float* __restrict__ u,     // [b][h][2500]
    const float* __restrict__ dv,    // [b][h][50]
    float* __restrict__ Bpart,       // [bh][2][51][132]
    float* __restrict__ aux)         // [bh][160]: F1[50] F2[50] rank[50]
{
  const int id = blockIdx.x;
  const int b  = (id & 7) + 8 * (id >> 8);   // XCD-locality for X slices
  const int h  = (id >> 3) & 31;
  const int tid = threadIdx.x;
  const int bh = b * 32 + h;

  __shared__ float2 sE[NS];          // sorted (e1,e2)   19.6 KB
  __shared__ unsigned short sIdx[NS];// sorted sat-index  4.9 KB
  __shared__ float sTheta[50], sD[50];
  __shared__ int   offs[52];
  __shared__ int   offCur[51];
  __shared__ float red[8];
  __shared__ float sMaxU;

  const float* uP = u + (size_t)bh * SAT + NT;   // skip ego rows
  if (tid < 50) sD[tid] = dv[(size_t)bh * NT + tid];
  if (tid < 51) offCur[tid] = 0;

  // ---- maxU (pass 1 over u, global; L2-hot 9.8KB) ----
  float mx = -1e30f;
  for (int i = tid; i < NS; i += 512) mx = fmaxf(mx, uP[i]);
  #pragma unroll
  for (int o = 32; o; o >>= 1) mx = fmaxf(mx, __shfl_xor(mx, o));
  if ((tid & 63) == 0) red[tid >> 6] = mx;
  __syncthreads();
  if (tid == 0) {
    float m2 = red[0];
    #pragma unroll
    for (int k = 1; k < 8; ++k) m2 = fmaxf(m2, red[k]);
    sMaxU = m2;
  }
  __syncthreads();
  const float maxU = sMaxU;

  // ---- theta rank-sort + per-query factors -> aux ----
  if (tid < 50) {
    float th = -sD[tid];
    int r = 0;
    for (int t2 = 0; t2 < 50; ++t2) {
      float th2 = -sD[t2];
      r += (th2 < th) || (th2 == th && t2 < tid);
    }
    sTheta[r] = th;
    float x = maxU + sD[tid];
    float L = (x >= 0.f) ? x : 0.2f * x;
    float* ax = aux + (size_t)bh * AUXW;
    ax[tid]       = __expf(x - L);         // F1
    ax[50 + tid]  = __expf(0.2f * x - L);  // F2
    ax[100 + tid] = (float)r;              // rank
  }
  __syncthreads();

  // ---- histogram (pass 2 over u) ----
  for (int i = tid; i < NS; i += 512) {
    float uu = uP[i];
    int lo = 0, hi = 50;
    while (lo < hi) { int mid = (lo + hi) >> 1; if (sTheta[mid] <= uu) lo = mid + 1; else hi = mid; }
    atomicAdd(&offCur[lo], 1);
  }
  __syncthreads();
  if (tid == 0) {
    int run = 0;
    for (int k = 0; k < 51; ++k) { int c = offCur[k]; offs[k] = run; run += c; }
    offs[51] = run;  // 2450
  }
  __syncthreads();
  if (tid < 51) offCur[tid] = offs[tid];
  __syncthreads();

  // ---- scatter (pass 3 over u): sorted (e1,e2,satIdx) ----
  for (int i = tid; i < NS; i += 512) {
    float uu = uP[i];
    int lo = 0, hi = 50;
    while (lo < hi) { int mid = (lo + hi) >> 1; if (sTheta[mid] <= uu) lo = mid + 1; else hi = mid; }
    int pos = atomicAdd(&offCur[lo], 1);
    sE[pos] = make_float2(__expf(uu - maxU), __expf(0.2f * (uu - maxU)));
    sIdx[pos] = (unsigned short)(i + NT);
  }
  __syncthreads();

  // ---- F: wave-owned segments, simple x4 unroll, flush to GLOBAL ----
  {
    const int wave = tid >> 6;        // 0..7
    const int lane = tid & 63;
    const int slot = lane >> 5;       // which source of the pair
    const int cq   = lane & 31;       // channel quad cq*4..+3
    const float* xb = X + (size_t)b * SAT * HIDK + cq * 4;
    float* bp = Bpart + (size_t)bh * BHW;

    for (int seg = wave; seg < 51; seg += 8) {
      const int i0 = offs[seg], i1 = offs[seg + 1];
      float a1[4] = {0.f, 0.f, 0.f, 0.f};
      float a2[4] = {0.f, 0.f, 0.f, 0.f};
      float z1 = 0.f, z2 = 0.f;
      int i = i0 + slot;
      for (; i + 6 < i1; i += 8) {
        float2 e0 = sE[i];     float2 e1 = sE[i + 2];
        float2 e2 = sE[i + 4]; float2 e3 = sE[i + 6];
        int s0 = sIdx[i];     int s1 = sIdx[i + 2];
        int s2 = sIdx[i + 4]; int s3 = sIdx[i + 6];
        float4 x0 = *(const float4*)(xb + (size_t)s0 * HIDK);
        float4 x1 = *(const float4*)(xb + (size_t)s1 * HIDK);
        float4 x2 = *(const float4*)(xb + (size_t)s2 * HIDK);
        float4 x3 = *(const float4*)(xb + (size_t)s3 * HIDK);
        a1[0] = fmaf(e0.x, x0.x, a1[0]); a1[1] = fmaf(e0.x, x0.y, a1[1]);
        a1[2] = fmaf(e0.x, x0.z, a1[2]); a1[3] = fmaf(e0.x, x0.w, a1[3]);
        a2[0] = fmaf(e0.y, x0.x, a2[0]); a2[1] = fmaf(e0.y, x0.y, a2[1]);
        a2[2] = fmaf(e0.y, x0.z, a2[2]); a2[3] = fmaf(e0.y, x0.w, a2[3]);
        z1 += e0.x; z2 += e0.y;
        a1[0] = fmaf(e1.x, x1.x, a1[0]); a1[1] = fmaf(e1.x, x1.y, a1[1]);
        a1[2] = fmaf(e1.x, x1.z, a1[2]); a1[3] = fmaf(e1.x, x1.w, a1[3]);
        a2[0] = fmaf(e1.y, x1.x, a2[0]); a2[1] = fmaf(e1.y, x1.y, a2[1]);
        a2[2] = fmaf(e1.y, x1.z, a2[2]); a2[3] = fmaf(e1.y, x1.w, a2[3]);
        z1 += e1.x; z2 += e1.y;
        a1[0] = fmaf(e2.x, x2.x, a1[0]); a1[1] = fmaf(e2.x, x2.y, a1[1]);
        a1[2] = fmaf(e2.x, x2.z, a1[2]); a1[3] = fmaf(e2.x, x2.w, a1[3]);
        a2[0] = fmaf(e2.y, x2.x, a2[0]); a2[1] = fmaf(e2.y, x2.y, a2[1]);
        a2[2] = fmaf(e2.y, x2.z, a2[2]); a2[3] = fmaf(e2.y, x2.w, a2[3]);
        z1 += e2.x; z2 += e2.y;
        a1[0] = fmaf(e3.x, x3.x, a1[0]); a1[1] = fmaf(e3.x, x3.y, a1[1]);
        a1[2] = fmaf(e3.x, x3.z, a1[2]); a1[3] = fmaf(e3.x, x3.w, a1[3]);
        a2[0] = fmaf(e3.y, x3.x, a2[0]); a2[1] = fmaf(e3.y, x3.y, a2[1]);
        a2[2] = fmaf(e3.y, x3.z, a2[2]); a2[3] = fmaf(e3.y, x3.w, a2[3]);
        z1 += e3.x; z2 += e3.y;
      }
      for (; i < i1; i += 2) {
        float2 e = sE[i];
        int s = sIdx[i];
        float4 xv = *(const float4*)(xb + (size_t)s * HIDK);
        a1[0] = fmaf(e.x, xv.x, a1[0]); a1[1] = fmaf(e.x, xv.y, a1[1]);
        a1[2] = fmaf(e.x, xv.z, a1[2]); a1[3] = fmaf(e.x, xv.w, a1[3]);
        a2[0] = fmaf(e.y, xv.x, a2[0]); a2[1] = fmaf(e.y, xv.y, a2[1]);
        a2[2] = fmaf(e.y, xv.z, a2[2]); a2[3] = fmaf(e.y, xv.w, a2[3]);
        z1 += e.x; z2 += e.y;
      }
      // combine slots; exclusive coalesced flush (no atomics)
      #pragma unroll
      for (int j = 0; j < 4; ++j) {
        a1[j] += __shfl_xor(a1[j], 32);
        a2[j] += __shfl_xor(a2[j], 32);
      }
      z1 += __shfl_xor(z1, 32);
      z2 += __shfl_xor(z2, 32);
      if (slot == 0) {
        float4 st1 = {a1[0], a1[1], a1[2], a1[3]};
        float4 st2 = {a2[0], a2[1], a2[2], a2[3]};
        *(float4*)&bp[seg * SEGW + cq * 4] = st1;
        *(float4*)&bp[WHICHW + seg * SEGW + cq * 4] = st2;
        if (cq == 0) {
          bp[seg * SEGW + 128] = z1;
          bp[WHICHW + seg * SEGW + 128] = z2;
        }
      }
    }
  }
}

// ============ K2b: scans + projection + ego write + bias fill ============
// 512 threads (was 256): at 62KB LDS only 2 blocks/CU fit, so 256 threads
// meant just 8 waves/CU — starved the write-bound fill. 512 -> 16 waves/CU.
__global__ __launch_bounds__(512) void k2b_out(
    const float* __restrict__ Bpart, const float* __restrict__ aux,
    const float* __restrict__ W, const float* __restrict__ bias,
    float* __restrict__ out)
{
  const int h = blockIdx.x & 31;
  const int b = blockIdx.x >> 5;
  const int bh = b * 32 + h;
  const int tid = threadIdx.x;

  __shared__ float Bb[2][51][SEGW];   // 53.9 KB
  __shared__ float WshT[128][16];     //  8.0 KB
  __shared__ float sF1[50], sF2[50];
  __shared__ int   sRank[50];
  __shared__ float sBias[512];

  // stage partials, aux, W_h^T, bias
  {
    const float4* src = (const float4*)(Bpart + (size_t)bh * BHW);
    float4* dst = (float4*)&Bb[0][0][0];
    for (int i = tid; i < BHW / 4; i += 512) dst[i] = src[i];
  }
  if (tid < 50) {
    const float* ax = aux + (size_t)bh * AUXW;
    sF1[tid] = ax[tid];
    sF2[tid] = ax[50 + tid];
    sRank[tid] = (int)ax[100 + tid];
  }
  {
    const float* Wh = W + (size_t)h * 16 * 128;
    for (int v = tid; v < 2048; v += 512) {
      int k = v >> 4, cout = v & 15;
      WshT[k][cout] = Wh[(size_t)cout * 128 + k];
    }
    if (tid < 512) sBias[tid] = bias[tid];
  }
  __syncthreads();

  // scans: which=0 -> exclusive suffix, which=1 -> inclusive prefix (129 ch)
  for (int task = tid; task < 258; task += 512) {
    int which = task >= 129;
    int c = task - which * 129;
    if (which == 0) {
      float run = 0.f;
      for (int k = 50; k >= 0; --k) { float tmp = Bb[0][k][c]; Bb[0][k][c] = run; run += tmp; }
    } else {
      float run = 0.f;
      for (int k = 0; k <= 50; ++k) { run += Bb[1][k][c]; Bb[1][k][c] = run; }
    }
  }

  // bias fill of this block's share of non-ego rows (independent of scans)
  {
    const int r0 = (NS * h) >> 5;
    const int r1 = (NS * (h + 1)) >> 5;
    const int n = (r1 - r0) * 128;
    float4* outp = (float4*)out;
    const float4* bv = (const float4*)sBias;
    for (int j = tid; j < n; j += 512) {
      int row = r0 + (j >> 7), c4 = j & 127;
      outp[((size_t)b * SAT + NT + row) * 128 + c4] = bv[c4];
    }
  }
  __syncthreads();

  // projection epilogue: 800 tasks grid-stride (R3 lesson)
  for (int task = tid; task < NT * NC; task += 512) {
    int t = task >> 4, cout = task & 15;
    int r = sRank[t];
    float F1 = sF1[t], F2 = sF2[t];
    float z = F1 * Bb[0][r][128] + F2 * Bb[1][r][128];
    const float* b1r = &Bb[0][r][0];
    const float* b2r = &Bb[1][r][0];
    float n1 = 0.f, n2 = 0.f;
    #pragma unroll 4
    for (int c = 0; c < 128; ++c) {
      float w = WshT[c][cout];
      n1 = fmaf(b1r[c], w, n1);
      n2 = fmaf(b2r[c], w, n2);
    }
    out[((size_t)b * SAT + t) * NOUT + h * 16 + cout] =
        (F1 * n1 + F2 * n2) / z + sBias[h * 16 + cout];
  }
}

extern "C" void kernel_launch(void* const* d_in, const int* in_sizes, int n_in,
                              void* d_out, int out_size, void* d_ws, size_t ws_size,
                              hipStream_t stream) {
  const float* X       = (const float*)d_in[0];  // h (32,50,50,128)
  const float* Wm      = (const float*)d_in[1];  // W (512,128)
  const float* att_src = (const float*)d_in[2];  // (32,16)
  const float* att_dst = (const float*)d_in[3];  // (32,16)
  const float* bias    = (const float*)d_in[4];  // (512,)
  float* out = (float*)d_out;

  // workspace: PQ 8192 | u 2.56M | dv 51.2K | aux 163.8K | Bpart 13.79M floats (~66.3 MB)
  float* PQ   = (float*)d_ws;
  float* u    = PQ + 64 * 128;
  float* dv   = u + (size_t)NB * NH * SAT;
  float* aux  = dv + (size_t)NB * NH * NT;
  float* Bpart = aux + (size_t)NB * NH * AUXW;

  hipLaunchKernelGGL(k0_pq, dim3(32), dim3(256), 0, stream, Wm, att_src, att_dst, PQ);
  hipLaunchKernelGGL(k1_ud, dim3(1250), dim3(256), 0, stream, X, PQ, u, dv);
  hipLaunchKernelGGL(k2a_gather, dim3(1024), dim3(512), 0, stream, X, u, dv, Bpart, aux);
  hipLaunchKernelGGL(k2b_out, dim3(1024), dim3(512), 0, stream, Bpart, aux, Wm, bias, out);
}